// Round 13
// baseline (212.245 us; speedup 1.0000x reference)
//
#include <hip/hip_runtime.h>

// Problem constants
#define V_N 1000000
#define J_N 23
#define BLK 256
#define NBLK 3907           // 3906 full 256-vertex tiles + tail (64 verts, wave 0 only)

// Output layout (flat fp32-element offsets):
// verts_batched (4,V,3) | pose (J,3) | joints_out (J,3) | scale (1) | displacement (3) | local_adjust (V,3)
#define OUT_POSE   12000000
#define OUT_JOINTS 12000069
#define OUT_SCALE  12000138
#define OUT_DISP   12000139
#define OUT_LA     12000142   // byte 48000568: 8B-aligned, NOT 16B-aligned

__device__ __constant__ int c_parents[J_N] = {
    -1, 0, 1, 1, 3, 4, 5, 4, 7, 4, 9, 1, 11, 12, 13, 12, 15, 12, 17, 0, 19, 0, 21
};

// Direct HBM->LDS DMA, 16B per lane, NT cache policy (aux=2). Dest must be
// wave-uniform base + lane*16 -- all call sites satisfy this (linear staging).
__device__ __forceinline__ void gload_lds16_nt(const void* g, void* l) {
    __builtin_amdgcn_global_load_lds(
        (const __attribute__((address_space(1))) unsigned int*)g,
        (__attribute__((address_space(3))) unsigned int*)l,
        16, 0, 2);
}

// ---------------- Stage 1: pose / Rodrigues / FK chain (tiny, 1 block) ----------------
__global__ void stage1_kernel(
    const float* __restrict__ joints_rest,
    const float* __restrict__ j0, const float* __restrict__ j1,
    const float* __restrict__ j2, const float* __restrict__ j3,
    const float* __restrict__ j4, const float* __restrict__ j5,
    const float* __restrict__ j12, const float* __restrict__ j13,
    const float* __restrict__ disp, const float* __restrict__ scale,
    const float* __restrict__ loc,
    float* __restrict__ wsA, float* __restrict__ out)
{
    __shared__ float jr[J_N][3];
    __shared__ float pose[J_N][3];
    __shared__ float R[J_N][9];
    __shared__ float rel[J_N][3];
    __shared__ float G[J_N][12];
    __shared__ float sb[4];
    const int t = threadIdx.x;

    if (t < J_N * 3) {
        ((float*)jr)[t]   = joints_rest[t];
        ((float*)pose)[t] = 0.0f;
    }
    __syncthreads();

    if (t < 27) {   // one thread per (pose row, component)
        const float PI = 3.14159265358979323846f;
        const int   rows[9] = { 0, 1, 2, 3, 11, 4, 5, 12, 13 };
        const float cf[9]   = { PI/2, PI/4, PI/9, PI/3, PI/3, PI/3, PI/3, PI/3, PI/3 };
        int i = t / 3, cmp = t % 3;
        const float* srcs[9];
        srcs[0]=j0; srcs[1]=j1; srcs[2]=j2; srcs[3]=j3; srcs[4]=j3;
        srcs[5]=j4; srcs[6]=j5; srcs[7]=j12; srcs[8]=j13;
        float syz = (rows[i] == 11 && cmp > 0) ? -1.0f : 1.0f;
        pose[rows[i]][cmp] = cf[i] * syz * tanhf(srcs[i][cmp]);
    }
    if (t == 32) {
        sb[0] = 0.0035f * scale[0];
        sb[1] = loc[0] + 0.1f * tanhf(disp[0]);
        sb[2] = loc[1] + 0.1f * tanhf(disp[1]);
        sb[3] = loc[2] + 0.1f * tanhf(disp[2]);
    }
    __syncthreads();

    if (t < J_N) {
        float rx = pose[t][0], ry = pose[t][1], rz = pose[t][2];
        float ang = sqrtf(rx*rx + ry*ry + rz*rz + 1e-12f);
        float inv = 1.0f / ang;
        float x = rx * inv, y = ry * inv, z = rz * inv;
        float s = sinf(ang), c = cosf(ang);
        float K[9]  = { 0.f, -z, y,  z, 0.f, -x,  -y, x, 0.f };
        float K2[9];
        for (int r = 0; r < 3; r++)
            for (int cc = 0; cc < 3; cc++) {
                float a = 0.f;
                for (int k = 0; k < 3; k++) a += K[r*3+k] * K[k*3+cc];
                K2[r*3+cc] = a;
            }
        for (int r = 0; r < 3; r++)
            for (int cc = 0; cc < 3; cc++) {
                float id = (r == cc) ? 1.f : 0.f;
                R[t][r*3+cc] = id + s * K[r*3+cc] + (1.f - c) * K2[r*3+cc];
            }
        int p = c_parents[t];
        for (int cc = 0; cc < 3; cc++)
            rel[t][cc] = (p < 0) ? jr[t][cc] : (jr[t][cc] - jr[p][cc]);
    }
    __syncthreads();

    if (t == 0) {  // serial FK chain (parents precede children)
        for (int r = 0; r < 3; r++) {
            for (int cc = 0; cc < 3; cc++) G[0][r*4+cc] = R[0][r*3+cc];
            G[0][r*4+3] = rel[0][r];
        }
        for (int j = 1; j < J_N; j++) {
            int p = c_parents[j];
            for (int r = 0; r < 3; r++) {
                float g0 = G[p][r*4+0], g1 = G[p][r*4+1], g2 = G[p][r*4+2], g3 = G[p][r*4+3];
                for (int cc = 0; cc < 3; cc++)
                    G[j][r*4+cc] = g0*R[j][0*3+cc] + g1*R[j][1*3+cc] + g2*R[j][2*3+cc];
                G[j][r*4+3] = g0*rel[j][0] + g1*rel[j][1] + g2*rel[j][2] + g3;
            }
        }
    }
    __syncthreads();

    if (t < J_N) {
        for (int r = 0; r < 3; r++) {
            float tc = G[t][r*4+0]*jr[t][0] + G[t][r*4+1]*jr[t][1] + G[t][r*4+2]*jr[t][2];
            wsA[t*12 + r*4 + 0] = G[t][r*4+0];
            wsA[t*12 + r*4 + 1] = G[t][r*4+1];
            wsA[t*12 + r*4 + 2] = G[t][r*4+2];
            wsA[t*12 + r*4 + 3] = G[t][r*4+3] - tc;
            out[OUT_JOINTS + t*3 + r] = sb[0] * G[t][r*4+3] + sb[1+r];
        }
    }
    if (t < J_N * 3) out[OUT_POSE + t] = ((const float*)pose)[t];
    if (t == 0) {
        wsA[276] = sb[0]; wsA[277] = sb[1]; wsA[278] = sb[2]; wsA[279] = sb[3];
        out[OUT_SCALE]  = scale[0];
        out[OUT_DISP+0] = disp[0]; out[OUT_DISP+1] = disp[1]; out[OUT_DISP+2] = disp[2];
    }
}

// ---------------- Stage 2: per-vertex skinning ----------------
// Round-13: r10 base (NT global_load_lds skin staging; last PASSING kernel,
// 210.0us) with the block-wide barrier replaced by per-wave autonomy.
// [r11/r12's persistent double-buffer failed the container twice with the
//  same source -> that family is abandoned as harness-unrunnable.]
//  - LDS is split into per-wave 5888B slices; each wave's 6 DMAs target only
//    its own slice, so the only wait needed is the wave's OWN vmcnt(0):
//    for global_load_lds, vmcnt retirement == LDS write complete, and the
//    wave's ds_reads issue after it in program order (m97 semantics).
//  - NO __syncthreads anywhere: the 24 waves/CU stage/drain/compute on their
//    own clocks, so the CU's read stream never pulses block-wide (r10's
//    residual structure). r6 tested decorrelation in the THRASH regime (null);
//    the regime changed in r9/r10, so it gets its one proper retry.
//  - Tail: wave-uniform guard vw < V_N (V_N%64==0) -- dead waves of block
//    3906 issue nothing, no OOB DMA.
//  - Math bit-identical -> absmax 0.
// NO launch_bounds (spill hazard on this toolchain).
__global__ void stage2_kernel(
    const float* __restrict__ vt,     // v_template   V*3 f32
    const float* __restrict__ skin,   // skinning     V*J f32
    const float* __restrict__ la,     // local_adjust V*3 f32
    const float* __restrict__ wsA,    // A[23][12] + {s, base.xyz}  (uniform reads)
    const int* __restrict__ bsp,      // batch_size
    float* __restrict__ out)
{
    __shared__ uint4 s_sk[4][368];    // 23552 B total -> 6 blocks/CU; per-wave slices

    const int tid  = threadIdx.x;
    const int lane = tid & 63;
    const int w    = tid >> 6;
    const int blk  = blockIdx.x;
    const int vw   = blk * BLK + (w << 6);   // wave's first vertex
    const int v    = vw + lane;

    if (vw >= V_N) return;            // whole-wave granularity (V_N % 64 == 0)

    // ---- this wave's skin slice: 368 uint4 via 6 DMAs (5 full + 48 lanes) ----
    {
        const uint4* g = (const uint4*)skin + (size_t)(vw >> 6) * 368;
        uint4* d = s_sk[w];
        gload_lds16_nt(g + lane,       d + lane);
        gload_lds16_nt(g + lane + 64,  d + lane + 64);
        gload_lds16_nt(g + lane + 128, d + lane + 128);
        gload_lds16_nt(g + lane + 192, d + lane + 192);
        gload_lds16_nt(g + lane + 256, d + lane + 256);
        if (lane < 48)
            gload_lds16_nt(g + lane + 320, d + lane + 320);
    }

    // ---- vt / la direct to registers (overlap the DMAs; drained together) ----
    const float* vp = vt + (size_t)v * 3;
    const float* lp = la + (size_t)v * 3;
    const float cvx = vp[0], cvy = vp[1], cvz = vp[2];
    const float clx = lp[0], cly = lp[1], clz = lp[2];

    // ---- per-wave drain: this wave's DMAs have landed in its own slice ----
    asm volatile("s_waitcnt vmcnt(0)" ::: "memory");

    {
        const float* wr = (const float*)s_sk[w] + lane * J_N;  // stride 23: 2-way alias, free
        float acc[12];
        #pragma unroll
        for (int k = 0; k < 12; k++) acc[k] = 0.f;
        #pragma unroll
        for (int j = 0; j < J_N; j++) {
            const float wj = wr[j];
            const float* Aj = wsA + j * 12;   // uniform address -> s_load, 0 VGPRs
            #pragma unroll
            for (int k = 0; k < 12; k++) acc[k] = fmaf(wj, Aj[k], acc[k]);
        }
        const float vx = cvx + 0.1f * tanhf(clx);
        const float vy = cvy + 0.1f * tanhf(cly);
        const float vz = cvz + 0.1f * tanhf(clz);
        const float px = acc[0]*vx + acc[1]*vy + acc[2]*vz  + acc[3];
        const float py = acc[4]*vx + acc[5]*vy + acc[6]*vz  + acc[7];
        const float pz = acc[8]*vx + acc[9]*vy + acc[10]*vz + acc[11];
        const float sc = wsA[276];            // uniform
        const float ox = fmaf(sc, px, wsA[277]);
        const float oy = fmaf(sc, py, wsA[278]);
        const float oz = fmaf(sc, pz, wsA[279]);

        const int bsz = bsp[0];
        float* ob = out + (size_t)v * 3;
        for (int b = 0; b < bsz; b++) {
            ob[0] = ox; ob[1] = oy; ob[2] = oz;   // dwordx3, coalesced, cacheable
            ob += 3000000;                        // V*3 floats per batch copy
        }
        float* oe = out + OUT_LA + (size_t)v * 3; // local_adjust passthrough
        oe[0] = clx; oe[1] = cly; oe[2] = clz;
    }
}

extern "C" void kernel_launch(void* const* d_in, const int* in_sizes, int n_in,
                              void* d_out, int out_size, void* d_ws, size_t ws_size,
                              hipStream_t stream) {
    const float* vt   = (const float*)d_in[0];
    const float* skin = (const float*)d_in[1];
    const float* jr   = (const float*)d_in[2];
    const float* j0   = (const float*)d_in[3];
    const float* j1   = (const float*)d_in[4];
    const float* j2   = (const float*)d_in[5];
    const float* j3   = (const float*)d_in[6];
    const float* j4   = (const float*)d_in[7];
    const float* j5   = (const float*)d_in[8];
    const float* j12  = (const float*)d_in[9];
    const float* j13  = (const float*)d_in[10];
    const float* la   = (const float*)d_in[11];
    const float* disp = (const float*)d_in[12];
    const float* sc   = (const float*)d_in[13];
    const float* loc  = (const float*)d_in[14];
    const int* bs     = (const int*)d_in[15];

    float* wsA = (float*)d_ws;
    float* out = (float*)d_out;

    stage1_kernel<<<1, 128, 0, stream>>>(jr, j0, j1, j2, j3, j4, j5, j12, j13,
                                         disp, sc, loc, wsA, out);
    stage2_kernel<<<NBLK, BLK, 0, stream>>>(vt, skin, la, wsA, bs, out);
}